// Round 1
// baseline (12207.925 us; speedup 1.0000x reference)
//
#include <hip/hip_runtime.h>

// HMM forward: alpha_t = (alpha_{t-1} @ A) * B[:, obs_t], out = sum(alpha_{T-1})
// S=2048 states, V=32768 obs symbols, T=4096 steps.
//
// Persistent cooperative kernel. A lives in VGPRs (64 floats/thread * 128
// blocks * 512 threads = 4M = all of A). Per step, the 2048-float alpha is
// exchanged through a global double buffer of {tag,value} 8-byte atomic pairs
// (data-as-flag: no fences, no cache invalidation, no separate flag round trip).

#define S 2048
#define V 32768
#define T 4096
#define G 128          // blocks (<= 256 CUs, cooperative => co-resident)
#define BT 512         // threads per block (8 waves)
#define COLS 16        // columns of A owned per block (2048/128)
#define RPT 64         // rows of A per thread (2048 / (512/16))
#define RING 16        // b-value ring slots
#define DIST 8         // b prefetch distance (steps)

__global__ __launch_bounds__(BT, 2) void hmm_fwd(
    const int* __restrict__ obs,
    const float* __restrict__ A,
    const float* __restrict__ B,
    const float* __restrict__ pi,
    float* __restrict__ out,
    unsigned long long* __restrict__ buf)   // 2 * S pairs of {tag32, f32}
{
    const int g    = blockIdx.x;
    const int tid  = threadIdx.x;
    const int lane = tid & 63;
    const int wave = tid >> 6;
    const int c    = tid & 15;        // column-within-block
    const int rg   = tid >> 4;        // row group 0..31 (64 rows each)
    const int j    = g * COLS + c;    // global column index

    // padded alpha: one float4 pad per 16 float4 (64 floats) -> conflict-free
    __shared__ float4 lds_alpha[544];          // 32*17
    __shared__ float  partial[8 * 16];         // per-wave column partials
    __shared__ float  bring[RING * 16];        // prefetched B[j, obs_t]

    // ---- load A fragment into registers: rows [rg*64, rg*64+64) of column j
    float a[RPT];
    {
        const float* Ap = A + (rg * RPT) * S + j;
#pragma unroll
        for (int k = 0; k < RPT; ++k) a[k] = Ap[k * S];
    }

    // ---- b-ring init for t = 1..DIST (wave 1)
    if (wave == 1 && lane < COLS) {
        for (int u = 1; u <= DIST; ++u) {
            int o = obs[u];
            bring[(u & (RING - 1)) * 16 + lane] = B[(g * COLS + lane) * V + o];
        }
    }

    // ---- alpha_0 = pi * B[:, obs_0]  (tag = 1)
    if (wave == 0 && lane < COLS) {
        int o0 = obs[0];
        float v = pi[j] * B[j * V + o0];
        unsigned long long p = (1ull << 32) | (unsigned long long)__float_as_uint(v);
        __hip_atomic_store(&buf[j], p, __ATOMIC_RELAXED, __HIP_MEMORY_SCOPE_AGENT);
    }

    for (int t = 1; t < T; ++t) {
        // ---- poll + stage alpha_{t-1} (tag == t); each thread owns 4 entries
        unsigned long long want = (unsigned long long)t;
        unsigned long long* src = buf + (((t - 1) & 1) * S) + 4 * tid;
        unsigned long long v0, v1, v2, v3;
        for (;;) {
            v0 = __hip_atomic_load(&src[0], __ATOMIC_RELAXED, __HIP_MEMORY_SCOPE_AGENT);
            v1 = __hip_atomic_load(&src[1], __ATOMIC_RELAXED, __HIP_MEMORY_SCOPE_AGENT);
            v2 = __hip_atomic_load(&src[2], __ATOMIC_RELAXED, __HIP_MEMORY_SCOPE_AGENT);
            v3 = __hip_atomic_load(&src[3], __ATOMIC_RELAXED, __HIP_MEMORY_SCOPE_AGENT);
            if ((v0 >> 32) == want && (v1 >> 32) == want &&
                (v2 >> 32) == want && (v3 >> 32) == want) break;
            __builtin_amdgcn_s_sleep(1);
        }
        float4 f;
        f.x = __uint_as_float((unsigned)v0);
        f.y = __uint_as_float((unsigned)v1);
        f.z = __uint_as_float((unsigned)v2);
        f.w = __uint_as_float((unsigned)v3);
        lds_alpha[tid + (tid >> 4)] = f;
        __syncthreads();   // B1: alpha staged

        // ---- prefetch b_{t+DIST} (wave 1, overlaps FMA below)
        if (wave == 1 && lane < COLS) {
            int tp = t + DIST;
            if (tp < T) {
                int o = obs[tp];
                bring[(tp & (RING - 1)) * 16 + lane] = B[(g * COLS + lane) * V + o];
            }
        }

        // ---- partial dot: 64 rows of column j
        float acc = 0.f;
        const int base = rg * 17;
#pragma unroll
        for (int k = 0; k < 16; ++k) {
            float4 al = lds_alpha[base + k];
            acc = fmaf(al.x, a[4 * k + 0], acc);
            acc = fmaf(al.y, a[4 * k + 1], acc);
            acc = fmaf(al.z, a[4 * k + 2], acc);
            acc = fmaf(al.w, a[4 * k + 3], acc);
        }
        // reduce lanes {c, c+16, c+32, c+48} within the wave
        acc += __shfl_down(acc, 32, 64);
        acc += __shfl_down(acc, 16, 64);
        if (lane < 16) partial[wave * 16 + lane] = acc;
        __syncthreads();   // B2: partials ready

        // ---- epilogue: wave 0 finishes column sums, applies b_t, publishes
        if (wave == 0 && lane < 16) {
            float s = 0.f;
#pragma unroll
            for (int w = 0; w < 8; ++w) s += partial[w * 16 + lane];
            float val = s * bring[(t & (RING - 1)) * 16 + lane];
            unsigned long long p = (((unsigned long long)(t + 1)) << 32) |
                                   (unsigned long long)__float_as_uint(val);
            __hip_atomic_store(&buf[(t & 1) * S + g * COLS + lane], p,
                               __ATOMIC_RELAXED, __HIP_MEMORY_SCOPE_AGENT);
        }
    }

    // ---- final: block 0 sums alpha_{T-1} (tag == T) into out[0]
    if (g == 0) {
        unsigned long long want = (unsigned long long)T;
        unsigned long long* src = buf + (((T - 1) & 1) * S) + 4 * tid;
        unsigned long long v0, v1, v2, v3;
        for (;;) {
            v0 = __hip_atomic_load(&src[0], __ATOMIC_RELAXED, __HIP_MEMORY_SCOPE_AGENT);
            v1 = __hip_atomic_load(&src[1], __ATOMIC_RELAXED, __HIP_MEMORY_SCOPE_AGENT);
            v2 = __hip_atomic_load(&src[2], __ATOMIC_RELAXED, __HIP_MEMORY_SCOPE_AGENT);
            v3 = __hip_atomic_load(&src[3], __ATOMIC_RELAXED, __HIP_MEMORY_SCOPE_AGENT);
            if ((v0 >> 32) == want && (v1 >> 32) == want &&
                (v2 >> 32) == want && (v3 >> 32) == want) break;
            __builtin_amdgcn_s_sleep(1);
        }
        float sm = __uint_as_float((unsigned)v0) + __uint_as_float((unsigned)v1) +
                   __uint_as_float((unsigned)v2) + __uint_as_float((unsigned)v3);
        sm += __shfl_down(sm, 32, 64);
        sm += __shfl_down(sm, 16, 64);
        sm += __shfl_down(sm, 8, 64);
        sm += __shfl_down(sm, 4, 64);
        sm += __shfl_down(sm, 2, 64);
        sm += __shfl_down(sm, 1, 64);
        if (lane == 0) partial[wave] = sm;   // safe: all tags==T implies our
        __syncthreads();                      // wave-0 epilogue reads are done
        if (tid == 0) {
            float tot = 0.f;
            for (int w = 0; w < 8; ++w) tot += partial[w];
            out[0] = tot;
        }
    }
}

extern "C" void kernel_launch(void* const* d_in, const int* in_sizes, int n_in,
                              void* d_out, int out_size, void* d_ws, size_t ws_size,
                              hipStream_t stream) {
    const int*   obs = (const int*)d_in[0];
    const float* A   = (const float*)d_in[1];
    const float* B   = (const float*)d_in[2];
    const float* pi  = (const float*)d_in[3];
    float* out = (float*)d_out;
    unsigned long long* buf = (unsigned long long*)d_ws;  // 2*S*8 = 32 KB

    // No memset needed: 0xAA poison gives tag 0xAAAAAAAA which never matches
    // any step tag in [1, 4096].

    void* args[] = { (void*)&obs, (void*)&A, (void*)&B, (void*)&pi,
                     (void*)&out, (void*)&buf };
    hipLaunchCooperativeKernel((void*)hmm_fwd, dim3(G), dim3(BT), args, 0, stream);
}